// Round 11
// baseline (136.121 us; speedup 1.0000x reference)
//
#include <hip/hip_runtime.h>
#include <math.h>

// Problem constants
#define BB 2
#define HH 64
#define WW 64
#define DM 128
#define EE 256
#define NN 16
#define RR 8
#define HW (HH*WW)          // 4096

__device__ __forceinline__ float gelu_exact(float v) {
    return 0.5f * v * (1.f + erff(v * 0.70710678118654752440f));
}
__device__ __forceinline__ float softplus_f(float v) {
    return fmaxf(v, 0.f) + log1pf(__expf(-fabsf(v)));
}

// DPP row_shr within 16-lane rows: lane L gets lane L-S (same row).
// old = 0 so invalid lanes (jj < S) read 0 under either bound_ctrl
// convention. Pure VALU, no LDS pipe.
template<int S>
__device__ __forceinline__ float dpp_shr0(float x) {
    return __int_as_float(__builtin_amdgcn_update_dpp(
        0, __float_as_int(x), 0x110 | S, 0xF, 0xF, false));
}

// ---------------------------------------------------------------------------
// K1a: u = gelu(x@ipw^T + ipb) -> u_t[B,E,H,W]. grid = 128 rows x 8 e-chunks.
// ---------------------------------------------------------------------------
__global__ __launch_bounds__(256) void k1a_u(
    const float* __restrict__ x,
    const float* __restrict__ ipw, const float* __restrict__ ipb,
    float* __restrict__ u_t)
{
    __shared__ float xs[64][129];

    const int blk = blockIdx.x;
    const int row = blk >> 3;            // b*64 + i
    const int ec  = blk & 7;
    const int b = row >> 6, i = row & 63;
    const int t = threadIdx.x;
    const int w = __builtin_amdgcn_readfirstlane(t >> 6);
    const int j = t & 63;

    const float* xrow = x + (size_t)row * (WW * DM);
    for (int idx = t; idx < WW * DM; idx += 256)
        xs[idx >> 7][idx & 127] = xrow[idx];
    __syncthreads();

    const int e0 = ec * 32 + w * 8;
    float acc[8];
    #pragma unroll
    for (int ee = 0; ee < 8; ++ee) acc[ee] = 0.f;

    for (int k = 0; k < DM; ++k) {
        const float xv = xs[j][k];
        #pragma unroll
        for (int ee = 0; ee < 8; ++ee)
            acc[ee] = fmaf(xv, ipw[(e0 + ee) * DM + k], acc[ee]);
    }
    #pragma unroll
    for (int ee = 0; ee < 8; ++ee) {
        const int e = e0 + ee;
        u_t[(((size_t)(b * EE + e) * HH + i) << 6) + j] = gelu_exact(acc[ee] + ipb[e]);
    }
}

// ---------------------------------------------------------------------------
// K1b1: dbc = u@xpw^T (+bias). 1024 blocks, 4 waves, K-split + LDS reduce.
// ---------------------------------------------------------------------------
__global__ __launch_bounds__(256) void k1b1_dbc(
    const float* __restrict__ u_t,
    const float* __restrict__ xpw, const float* __restrict__ xpb,
    float* __restrict__ dbc_g, float* __restrict__ Bm_t, float* __restrict__ Cm_t)
{
    __shared__ float xw[6][260];
    __shared__ float part[4][6][68];

    const int blk = blockIdx.x;
    const int cg = blk & 7;
    const int row = blk >> 3;            // b*64 + i
    const int b = row >> 6, i = row & 63;
    const int c0 = 6 * cg;
    const int t = threadIdx.x;
    const int w2 = __builtin_amdgcn_readfirstlane(t >> 6);
    const int j = t & 63;

    for (int idx = t; idx < 6 * 64; idx += 256) {
        const int cc = idx >> 6, e4 = idx & 63;
        *(float4*)&xw[cc][4 * e4] = ((const float4*)xpw)[(size_t)(c0 + cc) * 64 + e4];
    }
    __syncthreads();

    const float* ub = u_t + (((size_t)(b * EE)) << 12) + (i << 6) + j;
    const int ebase = 64 * w2;

    float acc[6] = {0.f, 0.f, 0.f, 0.f, 0.f, 0.f};
    for (int e4 = 0; e4 < 16; ++e4) {
        const int e = ebase + 4 * e4;
        const float u0 = ub[(size_t)(e + 0) << 12];
        const float u1 = ub[(size_t)(e + 1) << 12];
        const float u2 = ub[(size_t)(e + 2) << 12];
        const float u3 = ub[(size_t)(e + 3) << 12];
        #pragma unroll
        for (int cc = 0; cc < 6; ++cc) {
            const float4 wv = *(const float4*)&xw[cc][e];
            acc[cc] = fmaf(u0, wv.x, acc[cc]);
            acc[cc] = fmaf(u1, wv.y, acc[cc]);
            acc[cc] = fmaf(u2, wv.z, acc[cc]);
            acc[cc] = fmaf(u3, wv.w, acc[cc]);
        }
    }
    #pragma unroll
    for (int cc = 0; cc < 6; ++cc) part[w2][cc][j] = acc[cc];
    __syncthreads();

    for (int idx = t; idx < 6 * 64; idx += 256) {
        const int cc = idx >> 6, j2 = idx & 63;
        const int c = c0 + cc;
        const float s = ((part[0][cc][j2] + part[1][cc][j2]) +
                         (part[2][cc][j2] + part[3][cc][j2])) + xpb[c];
        if (c < 16) {
            dbc_g[((size_t)row * 16 + c) * 64 + j2] = s;
        } else if (c < 32) {
            const int n = c - 16;
            Bm_t[(((size_t)(b * NN + n) * HH + i) << 6) + j2] = s;
        } else {
            const int n = c - 32;
            Cm_t[(((size_t)(b * NN + n) * HH + i) << 6) + j2] = s;
        }
    }
}

// ---------------------------------------------------------------------------
// K1b2: deltaT/L = softplus(d@dtw^T + b). 512 blocks. e scalar -> s_loads.
// ---------------------------------------------------------------------------
__global__ __launch_bounds__(256) void k1b2_delta(
    const float* __restrict__ dbc_g,
    const float* __restrict__ dtTw, const float* __restrict__ dtTb,
    const float* __restrict__ dtLw, const float* __restrict__ dtLb,
    float* __restrict__ dT_t, float* __restrict__ dL_t)
{
    __shared__ float db[16][68];

    const int blk = blockIdx.x;
    const int eq = blk & 3;
    const int row = blk >> 2;            // b*64 + i
    const int b = row >> 6, i = row & 63;
    const int t = threadIdx.x;
    const int w2 = __builtin_amdgcn_readfirstlane(t >> 6);
    const int j = t & 63;

    for (int idx = t; idx < 16 * 64; idx += 256) {
        const int c = idx >> 6, j2 = idx & 63;
        db[c][j2] = dbc_g[((size_t)row * 16 + c) * 64 + j2];
    }
    __syncthreads();

    float dtv[8], dlv[8];
    #pragma unroll
    for (int r = 0; r < 8; ++r) { dtv[r] = db[r][j]; dlv[r] = db[8 + r][j]; }

    #pragma unroll 4
    for (int k = 0; k < 16; ++k) {
        const int e = 64 * eq + w2 + 4 * k;
        float sT = dtTb[e], sL = dtLb[e];
        #pragma unroll
        for (int r = 0; r < 8; ++r) {
            sT = fmaf(dtv[r], dtTw[e * RR + r], sT);
            sL = fmaf(dlv[r], dtLw[e * RR + r], sL);
        }
        dT_t[(((size_t)(b * EE + e) * HH + i) << 6) + j] = softplus_f(sT);
        dL_t[(((size_t)(b * EE + e) * HH + i) << 6) + j] = softplus_f(sL);
    }
}

// ---------------------------------------------------------------------------
// K2a: wavefront scan + chunked fused finalize. Block per (b,e): 4 waves.
// LDS cut to 16KB (parts[2][4][8][64], double-buffered 8-row chunks) so
// ~6 blocks/CU co-reside; __launch_bounds__(256,6) caps VGPR. TLP (not
// software prefetch) hides the HBM/L2 latency that held R9 at 2 waves/SIMD.
// One barrier per 8-row chunk (buffer parity removes the second).
// ---------------------------------------------------------------------------
__device__ __forceinline__ float row_scan_raw(
    float4 dT4, float4 dL4, float4 u4, float4 bm4, float4 cm4,
    float AT2, float AL2, float* h, int c, int jj)
{
    const float dTv[4] = {dT4.x, dT4.y, dT4.z, dT4.w};
    const float dLv[4] = {dL4.x, dL4.y, dL4.z, dL4.w};
    const float uv[4]  = {u4.x,  u4.y,  u4.z,  u4.w};
    const float bmv[4] = {bm4.x, bm4.y, bm4.z, bm4.w};
    const float cmv[4] = {cm4.x, cm4.y, cm4.z, cm4.w};

    float cumA[4], cumB[4];
    {
        const float aT = exp2f(dTv[0] * AT2);
        cumA[0] = exp2f(dLv[0] * AL2);
        cumB[0] = fmaf(aT, h[0], (dTv[0] + dLv[0]) * bmv[0] * uv[0]);
    }
    #pragma unroll
    for (int k = 1; k < 4; ++k) {
        const float aT = exp2f(dTv[k] * AT2);
        const float aL = exp2f(dLv[k] * AL2);
        const float bk = fmaf(aT, h[k], (dTv[k] + dLv[k]) * bmv[k] * uv[k]);
        cumB[k] = fmaf(aL, cumB[k - 1], bk);
        cumA[k] = aL * cumA[k - 1];
    }

    float Ag = cumA[3], Bg = cumB[3];
    { const float uA = dpp_shr0<1>(Ag), uB = dpp_shr0<1>(Bg);
      Bg = fmaf(Ag, uB, Bg); Ag *= (jj >= 1) ? uA : 1.f; }
    { const float uA = dpp_shr0<2>(Ag), uB = dpp_shr0<2>(Bg);
      Bg = fmaf(Ag, uB, Bg); Ag *= (jj >= 2) ? uA : 1.f; }
    { const float uA = dpp_shr0<4>(Ag), uB = dpp_shr0<4>(Bg);
      Bg = fmaf(Ag, uB, Bg); Ag *= (jj >= 4) ? uA : 1.f; }
    { const float uB = dpp_shr0<8>(Bg);
      Bg = fmaf(Ag, uB, Bg); }
    const float pB = dpp_shr0<1>(Bg);

    float g[4];
    #pragma unroll
    for (int k = 0; k < 4; ++k) {
        h[k] = fmaf(cumA[k], pB, cumB[k]);
        g[k] = h[k] * cmv[k];
    }
    #pragma unroll
    for (int k = 0; k < 4; ++k) {
        g[k] += __shfl_xor(g[k], 16, 64);
        g[k] += __shfl_xor(g[k], 32, 64);
    }
    return (c == 0) ? g[0] : (c == 1) ? g[1] : (c == 2) ? g[2] : g[3];
}

__global__ __launch_bounds__(256, 6) void k2a_scan(
    const float* __restrict__ u_t, const float* __restrict__ dT_t,
    const float* __restrict__ dL_t, const float* __restrict__ Bm_t,
    const float* __restrict__ Cm_t, const float* __restrict__ ATl,
    const float* __restrict__ ALl, const float* __restrict__ Dp,
    float* __restrict__ ys_t)
{
    __shared__ float parts[2][4][8][64];   // 16KB

    const int be = blockIdx.x;           // b*256 + e
    const int b = be >> 8, e = be & 255;
    const int t = threadIdx.x;
    const int w = __builtin_amdgcn_readfirstlane(t >> 6);
    const int lane = t & 63;
    const int c = lane >> 4, jj = lane & 15;
    const int n = w * 4 + c;
    const int col = 4 * jj + c;

    const float LOG2E = 1.44269504088896340736f;
    const float AT2 = -__expf(ATl[e * NN + n]) * LOG2E;
    const float AL2 = -__expf(ALl[e * NN + n]) * LOG2E;
    const float De = Dp[e];

    const float* dTp = dT_t + ((size_t)be << 12) + 4 * jj;
    const float* dLp = dL_t + ((size_t)be << 12) + 4 * jj;
    const float* up  = u_t  + ((size_t)be << 12) + 4 * jj;
    const float* bmp = Bm_t + ((size_t)(b * NN + n) << 12) + 4 * jj;
    const float* cmp = Cm_t + ((size_t)(b * NN + n) << 12) + 4 * jj;

    const int fcol = t & 63;
    const int frow = (t >> 6) * 2;
    const float* uf = u_t + ((size_t)be << 12) + fcol;
    float* ysf = ys_t + ((size_t)be << 12) + fcol;

    float h[4] = {0.f, 0.f, 0.f, 0.f};

    for (int ch = 0; ch < 8; ++ch) {
        const int buf = ch & 1;
        #pragma unroll
        for (int r = 0; r < 8; ++r) {
            const int off = (ch * 8 + r) << 6;
            const float4 dT4 = *(const float4*)(dTp + off);
            const float4 dL4 = *(const float4*)(dLp + off);
            const float4 u4  = *(const float4*)(up  + off);
            const float4 bm4 = *(const float4*)(bmp + off);
            const float4 cm4 = *(const float4*)(cmp + off);
            parts[buf][w][r][col] =
                row_scan_raw(dT4, dL4, u4, bm4, cm4, AT2, AL2, h, c, jj);
        }
        __syncthreads();
        #pragma unroll
        for (int q = 0; q < 2; ++q) {
            const int r = frow + q;
            const int i = ch * 8 + r;
            const float s = ((parts[buf][0][r][fcol] + parts[buf][1][r][fcol]) +
                             (parts[buf][2][r][fcol] + parts[buf][3][r][fcol]));
            ysf[i << 6] = gelu_exact(fmaf(uf[i << 6], De, s));
        }
    }
}

// ---------------------------------------------------------------------------
// K3: out projection. grid = 128 rows x 8 d-chunks of 16 (1024 blocks).
// ---------------------------------------------------------------------------
__global__ __launch_bounds__(256) void k3_outproj(
    const float* __restrict__ ys_t,
    const float* __restrict__ ow, const float* __restrict__ ob,
    float* __restrict__ out)
{
    __shared__ float ysL[64][65];

    const int blk = blockIdx.x;
    const int row = blk >> 3;
    const int dc  = blk & 7;
    const int b = row >> 6, i = row & 63;
    const int t = threadIdx.x;
    const int w = __builtin_amdgcn_readfirstlane(t >> 6);
    const int j = t & 63;
    const int d0 = dc * 16 + w * 4;

    float acc[4];
    #pragma unroll
    for (int dd = 0; dd < 4; ++dd) acc[dd] = 0.f;

    for (int ch = 0; ch < 4; ++ch) {
        __syncthreads();
        for (int idx = t; idx < 64 * 64; idx += 256) {
            const int ee = idx >> 6, jj = idx & 63;
            ysL[ee][jj] = ys_t[(((size_t)(b * EE + ch * 64 + ee) * HH + i) << 6) + jj];
        }
        __syncthreads();
        for (int e64 = 0; e64 < 64; ++e64) {
            const float yv = ysL[e64][j];
            const int e = ch * 64 + e64;
            #pragma unroll
            for (int dd = 0; dd < 4; ++dd)
                acc[dd] = fmaf(ow[(d0 + dd) * EE + e], yv, acc[dd]);
        }
    }

    float* orow = out + (size_t)row * (WW * DM) + (size_t)j * DM + d0;
    #pragma unroll
    for (int dd = 0; dd < 4; ++dd) orow[dd] = acc[dd] + ob[d0 + dd];
}

extern "C" void kernel_launch(void* const* d_in, const int* in_sizes, int n_in,
                              void* d_out, int out_size, void* d_ws, size_t ws_size,
                              hipStream_t stream) {
    const float* x    = (const float*)d_in[0];
    const float* ipw  = (const float*)d_in[1];
    const float* ipb  = (const float*)d_in[2];
    const float* xpw  = (const float*)d_in[3];
    const float* xpb  = (const float*)d_in[4];
    const float* dtTw = (const float*)d_in[5];
    const float* dtTb = (const float*)d_in[6];
    const float* dtLw = (const float*)d_in[7];
    const float* dtLb = (const float*)d_in[8];
    const float* ATl  = (const float*)d_in[9];
    const float* ALl  = (const float*)d_in[10];
    const float* Dp   = (const float*)d_in[11];
    const float* ow   = (const float*)d_in[12];
    const float* ob   = (const float*)d_in[13];
    float* out = (float*)d_out;

    float* ws    = (float*)d_ws;
    float* u_t   = ws;
    float* dT_t  = u_t  + (size_t)BB * EE * HW;
    float* dL_t  = dT_t + (size_t)BB * EE * HW;
    float* ys_t  = dL_t + (size_t)BB * EE * HW;
    float* Bm_t  = ys_t + (size_t)BB * EE * HW;
    float* Cm_t  = Bm_t + (size_t)BB * NN * HW;
    float* dbc_g = Cm_t + (size_t)BB * NN * HW;   // [128][16][64]

    k1a_u<<<BB * HH * 8, 256, 0, stream>>>(x, ipw, ipb, u_t);
    k1b1_dbc<<<BB * HH * 8, 256, 0, stream>>>(u_t, xpw, xpb, dbc_g, Bm_t, Cm_t);
    k1b2_delta<<<BB * HH * 4, 256, 0, stream>>>(dbc_g, dtTw, dtTb, dtLw, dtLb,
                                                dT_t, dL_t);
    k2a_scan<<<BB * EE, 256, 0, stream>>>(u_t, dT_t, dL_t, Bm_t, Cm_t,
                                          ATl, ALl, Dp, ys_t);
    k3_outproj<<<BB * HH * 8, 256, 0, stream>>>(ys_t, ow, ob, out);
}

// Round 12
// 128.981 us; speedup vs baseline: 1.0554x; 1.0554x over previous
//
#include <hip/hip_runtime.h>
#include <math.h>

// Problem constants
#define BB 2
#define HH 64
#define WW 64
#define DM 128
#define EE 256
#define NN 16
#define RR 8
#define HW (HH*WW)          // 4096
#define CH 16               // k2a rows per pipeline chunk
#define NCH (HH/CH)         // 4 chunks

__device__ __forceinline__ float gelu_exact(float v) {
    return 0.5f * v * (1.f + erff(v * 0.70710678118654752440f));
}
__device__ __forceinline__ float softplus_f(float v) {
    return fmaxf(v, 0.f) + log1pf(__expf(-fabsf(v)));
}

// DPP row_shr within 16-lane rows: lane L gets lane L-S (same row).
// old = 0 so invalid lanes (jj < S) read 0 under either bound_ctrl
// convention. Pure VALU, no LDS pipe.
template<int S>
__device__ __forceinline__ float dpp_shr0(float x) {
    return __int_as_float(__builtin_amdgcn_update_dpp(
        0, __float_as_int(x), 0x110 | S, 0xF, 0xF, false));
}

// ---------------------------------------------------------------------------
// K1a: u = gelu(x@ipw^T + ipb) -> u_t[B,E,H,W]. grid = 128 rows x 8 e-chunks.
// ---------------------------------------------------------------------------
__global__ __launch_bounds__(256) void k1a_u(
    const float* __restrict__ x,
    const float* __restrict__ ipw, const float* __restrict__ ipb,
    float* __restrict__ u_t)
{
    __shared__ float xs[64][129];

    const int blk = blockIdx.x;
    const int row = blk >> 3;            // b*64 + i
    const int ec  = blk & 7;
    const int b = row >> 6, i = row & 63;
    const int t = threadIdx.x;
    const int w = __builtin_amdgcn_readfirstlane(t >> 6);
    const int j = t & 63;

    const float* xrow = x + (size_t)row * (WW * DM);
    for (int idx = t; idx < WW * DM; idx += 256)
        xs[idx >> 7][idx & 127] = xrow[idx];
    __syncthreads();

    const int e0 = ec * 32 + w * 8;
    float acc[8];
    #pragma unroll
    for (int ee = 0; ee < 8; ++ee) acc[ee] = 0.f;

    for (int k = 0; k < DM; ++k) {
        const float xv = xs[j][k];
        #pragma unroll
        for (int ee = 0; ee < 8; ++ee)
            acc[ee] = fmaf(xv, ipw[(e0 + ee) * DM + k], acc[ee]);
    }
    #pragma unroll
    for (int ee = 0; ee < 8; ++ee) {
        const int e = e0 + ee;
        u_t[(((size_t)(b * EE + e) * HH + i) << 6) + j] = gelu_exact(acc[ee] + ipb[e]);
    }
}

// ---------------------------------------------------------------------------
// K1b1: dbc = u@xpw^T (+bias). 1024 blocks, 4 waves, K-split + LDS reduce.
// ---------------------------------------------------------------------------
__global__ __launch_bounds__(256) void k1b1_dbc(
    const float* __restrict__ u_t,
    const float* __restrict__ xpw, const float* __restrict__ xpb,
    float* __restrict__ dbc_g, float* __restrict__ Bm_t, float* __restrict__ Cm_t)
{
    __shared__ float xw[6][260];
    __shared__ float part[4][6][68];

    const int blk = blockIdx.x;
    const int cg = blk & 7;
    const int row = blk >> 3;            // b*64 + i
    const int b = row >> 6, i = row & 63;
    const int c0 = 6 * cg;
    const int t = threadIdx.x;
    const int w2 = __builtin_amdgcn_readfirstlane(t >> 6);
    const int j = t & 63;

    for (int idx = t; idx < 6 * 64; idx += 256) {
        const int cc = idx >> 6, e4 = idx & 63;
        *(float4*)&xw[cc][4 * e4] = ((const float4*)xpw)[(size_t)(c0 + cc) * 64 + e4];
    }
    __syncthreads();

    const float* ub = u_t + (((size_t)(b * EE)) << 12) + (i << 6) + j;
    const int ebase = 64 * w2;

    float acc[6] = {0.f, 0.f, 0.f, 0.f, 0.f, 0.f};
    for (int e4 = 0; e4 < 16; ++e4) {
        const int e = ebase + 4 * e4;
        const float u0 = ub[(size_t)(e + 0) << 12];
        const float u1 = ub[(size_t)(e + 1) << 12];
        const float u2 = ub[(size_t)(e + 2) << 12];
        const float u3 = ub[(size_t)(e + 3) << 12];
        #pragma unroll
        for (int cc = 0; cc < 6; ++cc) {
            const float4 wv = *(const float4*)&xw[cc][e];
            acc[cc] = fmaf(u0, wv.x, acc[cc]);
            acc[cc] = fmaf(u1, wv.y, acc[cc]);
            acc[cc] = fmaf(u2, wv.z, acc[cc]);
            acc[cc] = fmaf(u3, wv.w, acc[cc]);
        }
    }
    #pragma unroll
    for (int cc = 0; cc < 6; ++cc) part[w2][cc][j] = acc[cc];
    __syncthreads();

    for (int idx = t; idx < 6 * 64; idx += 256) {
        const int cc = idx >> 6, j2 = idx & 63;
        const int c = c0 + cc;
        const float s = ((part[0][cc][j2] + part[1][cc][j2]) +
                         (part[2][cc][j2] + part[3][cc][j2])) + xpb[c];
        if (c < 16) {
            dbc_g[((size_t)row * 16 + c) * 64 + j2] = s;
        } else if (c < 32) {
            const int n = c - 16;
            Bm_t[(((size_t)(b * NN + n) * HH + i) << 6) + j2] = s;
        } else {
            const int n = c - 32;
            Cm_t[(((size_t)(b * NN + n) * HH + i) << 6) + j2] = s;
        }
    }
}

// ---------------------------------------------------------------------------
// K1b2: deltaT/L = softplus(d@dtw^T + b). 512 blocks. e scalar -> s_loads.
// ---------------------------------------------------------------------------
__global__ __launch_bounds__(256) void k1b2_delta(
    const float* __restrict__ dbc_g,
    const float* __restrict__ dtTw, const float* __restrict__ dtTb,
    const float* __restrict__ dtLw, const float* __restrict__ dtLb,
    float* __restrict__ dT_t, float* __restrict__ dL_t)
{
    __shared__ float db[16][68];

    const int blk = blockIdx.x;
    const int eq = blk & 3;
    const int row = blk >> 2;            // b*64 + i
    const int b = row >> 6, i = row & 63;
    const int t = threadIdx.x;
    const int w2 = __builtin_amdgcn_readfirstlane(t >> 6);
    const int j = t & 63;

    for (int idx = t; idx < 16 * 64; idx += 256) {
        const int c = idx >> 6, j2 = idx & 63;
        db[c][j2] = dbc_g[((size_t)row * 16 + c) * 64 + j2];
    }
    __syncthreads();

    float dtv[8], dlv[8];
    #pragma unroll
    for (int r = 0; r < 8; ++r) { dtv[r] = db[r][j]; dlv[r] = db[8 + r][j]; }

    #pragma unroll 4
    for (int k = 0; k < 16; ++k) {
        const int e = 64 * eq + w2 + 4 * k;
        float sT = dtTb[e], sL = dtLb[e];
        #pragma unroll
        for (int r = 0; r < 8; ++r) {
            sT = fmaf(dtv[r], dtTw[e * RR + r], sT);
            sL = fmaf(dlv[r], dtLw[e * RR + r], sL);
        }
        dT_t[(((size_t)(b * EE + e) * HH + i) << 6) + j] = softplus_f(sT);
        dL_t[(((size_t)(b * EE + e) * HH + i) << 6) + j] = softplus_f(sL);
    }
}

// ---------------------------------------------------------------------------
// K2a: wavefront scan, LDS-pipelined (T14 async-STAGE). Block per (b,e):
// 4 waves. Per 16-row chunk: issue next chunk's dT/dL/u global loads
// (3 float4/thread, sched_barrier fence so they can't sink), compute 16
// rows from the current LDS stage buffer (broadcast ds_reads), ds_write
// the next chunk (compiler vmcnt covers the latency under the compute),
// ONE barrier/chunk, then chunk-granular fused finalize (parity-safe:
// finalize reads only parts[buf] + global u). bm/cm are L2-resident
// (512KB shared) and keep distance-1 register prefetch.
// ---------------------------------------------------------------------------
__device__ __forceinline__ float row_scan_raw(
    float4 dT4, float4 dL4, float4 u4, float4 bm4, float4 cm4,
    float AT2, float AL2, float* h, int c, int jj)
{
    const float dTv[4] = {dT4.x, dT4.y, dT4.z, dT4.w};
    const float dLv[4] = {dL4.x, dL4.y, dL4.z, dL4.w};
    const float uv[4]  = {u4.x,  u4.y,  u4.z,  u4.w};
    const float bmv[4] = {bm4.x, bm4.y, bm4.z, bm4.w};
    const float cmv[4] = {cm4.x, cm4.y, cm4.z, cm4.w};

    float cumA[4], cumB[4];
    {
        const float aT = exp2f(dTv[0] * AT2);
        cumA[0] = exp2f(dLv[0] * AL2);
        cumB[0] = fmaf(aT, h[0], (dTv[0] + dLv[0]) * bmv[0] * uv[0]);
    }
    #pragma unroll
    for (int k = 1; k < 4; ++k) {
        const float aT = exp2f(dTv[k] * AT2);
        const float aL = exp2f(dLv[k] * AL2);
        const float bk = fmaf(aT, h[k], (dTv[k] + dLv[k]) * bmv[k] * uv[k]);
        cumB[k] = fmaf(aL, cumB[k - 1], bk);
        cumA[k] = aL * cumA[k - 1];
    }

    float Ag = cumA[3], Bg = cumB[3];
    { const float uA = dpp_shr0<1>(Ag), uB = dpp_shr0<1>(Bg);
      Bg = fmaf(Ag, uB, Bg); Ag *= (jj >= 1) ? uA : 1.f; }
    { const float uA = dpp_shr0<2>(Ag), uB = dpp_shr0<2>(Bg);
      Bg = fmaf(Ag, uB, Bg); Ag *= (jj >= 2) ? uA : 1.f; }
    { const float uA = dpp_shr0<4>(Ag), uB = dpp_shr0<4>(Bg);
      Bg = fmaf(Ag, uB, Bg); Ag *= (jj >= 4) ? uA : 1.f; }
    { const float uB = dpp_shr0<8>(Bg);
      Bg = fmaf(Ag, uB, Bg); }
    const float pB = dpp_shr0<1>(Bg);

    float g[4];
    #pragma unroll
    for (int k = 0; k < 4; ++k) {
        h[k] = fmaf(cumA[k], pB, cumB[k]);
        g[k] = h[k] * cmv[k];
    }
    #pragma unroll
    for (int k = 0; k < 4; ++k) {
        g[k] += __shfl_xor(g[k], 16, 64);
        g[k] += __shfl_xor(g[k], 32, 64);
    }
    return (c == 0) ? g[0] : (c == 1) ? g[1] : (c == 2) ? g[2] : g[3];
}

__global__ __launch_bounds__(256, 2) void k2a_scan(
    const float* __restrict__ u_t, const float* __restrict__ dT_t,
    const float* __restrict__ dL_t, const float* __restrict__ Bm_t,
    const float* __restrict__ Cm_t, const float* __restrict__ ATl,
    const float* __restrict__ ALl, const float* __restrict__ Dp,
    float* __restrict__ ys_t)
{
    __shared__ float sdT[2][CH][64];      // 8KB
    __shared__ float sdL[2][CH][64];      // 8KB
    __shared__ float su [2][CH][64];      // 8KB
    __shared__ float parts[2][4][CH][64]; // 32KB   (total 56KB -> 2 blocks/CU)

    const int be = blockIdx.x;           // b*256 + e
    const int b = be >> 8, e = be & 255;
    const int t = threadIdx.x;
    const int w = __builtin_amdgcn_readfirstlane(t >> 6);
    const int lane = t & 63;
    const int c = lane >> 4, jj = lane & 15;
    const int n = w * 4 + c;
    const int col = 4 * jj + c;

    const float LOG2E = 1.44269504088896340736f;
    const float AT2 = -__expf(ATl[e * NN + n]) * LOG2E;
    const float AL2 = -__expf(ALl[e * NN + n]) * LOG2E;
    const float De = Dp[e];

    const float* dTg = dT_t + ((size_t)be << 12);
    const float* dLg = dL_t + ((size_t)be << 12);
    const float* ug  = u_t  + ((size_t)be << 12);
    const float* bmp = Bm_t + ((size_t)(b * NN + n) << 12) + 4 * jj;
    const float* cmp = Cm_t + ((size_t)(b * NN + n) << 12) + 4 * jj;

    // stage loader role: thread t owns float4 slot t of each stream chunk
    const int srow = t >> 4;             // 0..15
    const int scol = (t & 15) << 2;      // 0,4,..,60

    // finalize role
    const int fcol = t & 63;
    const float* uf = ug + fcol;
    float* ysf = ys_t + ((size_t)be << 12) + fcol;

    float4 ldT, ldL, lu;
    {   // prolog: stage chunk 0
        const size_t off = ((size_t)srow << 6) + scol;
        ldT = *(const float4*)(dTg + off);
        ldL = *(const float4*)(dLg + off);
        lu  = *(const float4*)(ug  + off);
        *(float4*)&sdT[0][srow][scol] = ldT;
        *(float4*)&sdL[0][srow][scol] = ldL;
        *(float4*)&su [0][srow][scol] = lu;
    }
    __syncthreads();

    // bm/cm distance-1 register prefetch (L2-resident streams)
    float4 bm4 = *(const float4*)(bmp);
    float4 cm4 = *(const float4*)(cmp);

    float h[4] = {0.f, 0.f, 0.f, 0.f};

    for (int ch = 0; ch < NCH; ++ch) {
        const int buf = ch & 1;

        if (ch + 1 < NCH) {   // issue next chunk's loads; fence against sinking
            const size_t off = ((size_t)((ch + 1) * CH + srow) << 6) + scol;
            ldT = *(const float4*)(dTg + off);
            ldL = *(const float4*)(dLg + off);
            lu  = *(const float4*)(ug  + off);
            __builtin_amdgcn_sched_barrier(0);
        }

        #pragma unroll
        for (int r = 0; r < CH; ++r) {
            const int i = ch * CH + r;
            const int ipn = (i + 1 < HH) ? i + 1 : i;
            const float4 bm4n = *(const float4*)(bmp + (ipn << 6));
            const float4 cm4n = *(const float4*)(cmp + (ipn << 6));

            const float4 dT4 = *(const float4*)&sdT[buf][r][4 * jj];
            const float4 dL4 = *(const float4*)&sdL[buf][r][4 * jj];
            const float4 u4  = *(const float4*)&su [buf][r][4 * jj];

            parts[buf][w][r][col] =
                row_scan_raw(dT4, dL4, u4, bm4, cm4, AT2, AL2, h, c, jj);

            bm4 = bm4n; cm4 = cm4n;
        }

        if (ch + 1 < NCH) {   // write next chunk into the other stage buffer
            *(float4*)&sdT[buf ^ 1][srow][scol] = ldT;
            *(float4*)&sdL[buf ^ 1][srow][scol] = ldL;
            *(float4*)&su [buf ^ 1][srow][scol] = lu;
        }
        __syncthreads();

        // chunk-granular fused finalize: 4 rows per thread-row-group.
        // Reads only parts[buf] (not written next chunk) + global u (L3-warm).
        #pragma unroll
        for (int q = 0; q < 4; ++q) {
            const int r = (t >> 6) * 4 + q;
            const int i = ch * CH + r;
            const float s = ((parts[buf][0][r][fcol] + parts[buf][1][r][fcol]) +
                             (parts[buf][2][r][fcol] + parts[buf][3][r][fcol]));
            ysf[i << 6] = gelu_exact(fmaf(uf[i << 6], De, s));
        }
    }
}

// ---------------------------------------------------------------------------
// K3: out projection. grid = 128 rows x 4 d-chunks (R9 config).
// ---------------------------------------------------------------------------
__global__ __launch_bounds__(256) void k3_outproj(
    const float* __restrict__ ys_t,
    const float* __restrict__ ow, const float* __restrict__ ob,
    float* __restrict__ out)
{
    __shared__ float ysL[64][65];

    const int blk = blockIdx.x;
    const int row = blk >> 2;
    const int dc  = blk & 3;
    const int b = row >> 6, i = row & 63;
    const int t = threadIdx.x;
    const int w = __builtin_amdgcn_readfirstlane(t >> 6);
    const int j = t & 63;
    const int d0 = dc * 32 + w * 8;

    float acc[8];
    #pragma unroll
    for (int dd = 0; dd < 8; ++dd) acc[dd] = 0.f;

    for (int ch = 0; ch < 4; ++ch) {
        __syncthreads();
        for (int idx = t; idx < 64 * 64; idx += 256) {
            const int ee = idx >> 6, jj = idx & 63;
            ysL[ee][jj] = ys_t[(((size_t)(b * EE + ch * 64 + ee) * HH + i) << 6) + jj];
        }
        __syncthreads();
        for (int e64 = 0; e64 < 64; ++e64) {
            const float yv = ysL[e64][j];
            const int e = ch * 64 + e64;
            #pragma unroll
            for (int dd = 0; dd < 8; ++dd)
                acc[dd] = fmaf(ow[(d0 + dd) * EE + e], yv, acc[dd]);
        }
    }

    float* orow = out + (size_t)row * (WW * DM) + (size_t)j * DM + d0;
    #pragma unroll
    for (int dd = 0; dd < 8; ++dd) orow[dd] = acc[dd] + ob[d0 + dd];
}

extern "C" void kernel_launch(void* const* d_in, const int* in_sizes, int n_in,
                              void* d_out, int out_size, void* d_ws, size_t ws_size,
                              hipStream_t stream) {
    const float* x    = (const float*)d_in[0];
    const float* ipw  = (const float*)d_in[1];
    const float* ipb  = (const float*)d_in[2];
    const float* xpw  = (const float*)d_in[3];
    const float* xpb  = (const float*)d_in[4];
    const float* dtTw = (const float*)d_in[5];
    const float* dtTb = (const float*)d_in[6];
    const float* dtLw = (const float*)d_in[7];
    const float* dtLb = (const float*)d_in[8];
    const float* ATl  = (const float*)d_in[9];
    const float* ALl  = (const float*)d_in[10];
    const float* Dp   = (const float*)d_in[11];
    const float* ow   = (const float*)d_in[12];
    const float* ob   = (const float*)d_in[13];
    float* out = (float*)d_out;

    float* ws    = (float*)d_ws;
    float* u_t   = ws;
    float* dT_t  = u_t  + (size_t)BB * EE * HW;
    float* dL_t  = dT_t + (size_t)BB * EE * HW;
    float* ys_t  = dL_t + (size_t)BB * EE * HW;
    float* Bm_t  = ys_t + (size_t)BB * EE * HW;
    float* Cm_t  = Bm_t + (size_t)BB * NN * HW;
    float* dbc_g = Cm_t + (size_t)BB * NN * HW;   // [128][16][64]

    k1a_u<<<BB * HH * 8, 256, 0, stream>>>(x, ipw, ipb, u_t);
    k1b1_dbc<<<BB * HH * 8, 256, 0, stream>>>(u_t, xpw, xpb, dbc_g, Bm_t, Cm_t);
    k1b2_delta<<<BB * HH * 4, 256, 0, stream>>>(dbc_g, dtTw, dtTb, dtLw, dtLb,
                                                dT_t, dL_t);
    k2a_scan<<<BB * EE, 256, 0, stream>>>(u_t, dT_t, dL_t, Bm_t, Cm_t,
                                          ATl, ALl, Dp, ys_t);
    k3_outproj<<<BB * HH * 4, 256, 0, stream>>>(ys_t, ow, ob, out);
}